// Round 1
// baseline (2163.194 us; speedup 1.0000x reference)
//
#include <hip/hip_runtime.h>
#include <hip/hip_bf16.h>

// ---------------------------------------------------------------------------
// GraphTransformerBlock: TransformerConv(H=2, C=128) + skip + LN + FFN + LN
// Strategy:
//   q,k,v,skip : fp32 tiled GEMMs
//   P = q @ We_h            (so alpha needs no per-edge e projection)
//   pass A: alpha[e,h] = (q[d]·k[s] + P[d,h]·ea[e]) / sqrt(128), atomicMax amax
//   pass B: ex = exp(alpha - amax[d]), atomicAdd denom
//   pass C: agg[d] += w*v[s] (atomics), wea[d,h,:] += w*ea[e,:] (atomics)
//   econ   : agg[:,h,:] += wea[:,h,:] @ We_h^T   (GEMM, moves e-projection to nodes)
//   node   : h = LN1(x + 0.5*(agg0+agg1) + skip); FFN GEMMs; out = LN2(h+f)
// ---------------------------------------------------------------------------

#define TILE_BK 16

template<int ACT, int ADD>
__global__ __launch_bounds__(256)
void gemm_tn(const float* __restrict__ A, int lda,
             const float* __restrict__ W, int ldw,
             const float* __restrict__ bias,
             float* __restrict__ out, int ldo,
             int M, int K, int OC) {
    // C[M,OC] = act(A[M,K] @ W[OC,K]^T + bias), optional +=
    __shared__ float As[TILE_BK][68];   // transposed [k][m], stride 68 keeps 16B align
    __shared__ float Ws[TILE_BK][68];
    const int tid = threadIdx.x;
    const int tx = tid & 15, ty = tid >> 4;
    const int row0 = blockIdx.y * 64, col0 = blockIdx.x * 64;
    const int lr = tid >> 2, lc = (tid & 3) * 4;
    const int gr = row0 + lr;
    const int gc = col0 + lr;
    const float* aBase = A + (size_t)gr * lda + lc;
    const float* wBase = W + (size_t)gc * ldw + lc;
    const bool aOk = (gr < M);
    const bool wOk = (gc < OC);
    float acc[4][4] = {{0.f}};
    for (int kt = 0; kt < K; kt += TILE_BK) {
        float4 av = aOk ? *(const float4*)(aBase + kt) : make_float4(0.f,0.f,0.f,0.f);
        float4 wv = wOk ? *(const float4*)(wBase + kt) : make_float4(0.f,0.f,0.f,0.f);
        __syncthreads();
        As[lc+0][lr] = av.x; As[lc+1][lr] = av.y; As[lc+2][lr] = av.z; As[lc+3][lr] = av.w;
        Ws[lc+0][lr] = wv.x; Ws[lc+1][lr] = wv.y; Ws[lc+2][lr] = wv.z; Ws[lc+3][lr] = wv.w;
        __syncthreads();
        #pragma unroll
        for (int kk = 0; kk < TILE_BK; kk++) {
            float4 a = *(const float4*)&As[kk][ty*4];
            float4 b = *(const float4*)&Ws[kk][tx*4];
            acc[0][0] += a.x*b.x; acc[0][1] += a.x*b.y; acc[0][2] += a.x*b.z; acc[0][3] += a.x*b.w;
            acc[1][0] += a.y*b.x; acc[1][1] += a.y*b.y; acc[1][2] += a.y*b.z; acc[1][3] += a.y*b.w;
            acc[2][0] += a.z*b.x; acc[2][1] += a.z*b.y; acc[2][2] += a.z*b.z; acc[2][3] += a.z*b.w;
            acc[3][0] += a.w*b.x; acc[3][1] += a.w*b.y; acc[3][2] += a.w*b.z; acc[3][3] += a.w*b.w;
        }
    }
    #pragma unroll
    for (int i = 0; i < 4; i++) {
        int r = row0 + ty*4 + i;
        if (r >= M) continue;
        #pragma unroll
        for (int j = 0; j < 4; j++) {
            int c = col0 + tx*4 + j;
            if (c >= OC) continue;
            float v = acc[i][j] + (bias ? bias[c] : 0.f);
            if (ACT == 1) v = (v > 0.f) ? v : 0.01f * v;
            if (ADD) out[(size_t)r*ldo + c] += v;
            else     out[(size_t)r*ldo + c]  = v;
        }
    }
}

__global__ void transpose_we(const float* __restrict__ We, float* __restrict__ WeT) {
    int i = blockIdx.x * blockDim.x + threadIdx.x;   // 2*32*128 = 8192
    if (i < 8192) {
        int h = i >> 12, rem = i & 4095, t = rem >> 7, c = rem & 127;
        WeT[i] = We[(size_t)(h*128 + c) * 32 + t];
    }
}

__global__ void init_nd(unsigned* __restrict__ amax, float* __restrict__ den, int n) {
    int i = blockIdx.x * blockDim.x + threadIdx.x;
    if (i < n) { amax[i] = 0x007FFFFFu; den[i] = 0.f; }   // ord(-inf)
}

__global__ void zero_f(float* __restrict__ p, int n) {
    int i = blockIdx.x * blockDim.x + threadIdx.x;
    if (i < n) p[i] = 0.f;
}

__device__ __forceinline__ unsigned ord_encode(float f) {
    unsigned u = __float_as_uint(f);
    return (u & 0x80000000u) ? ~u : (u | 0x80000000u);
}
__device__ __forceinline__ float ord_decode(unsigned u) {
    unsigned v = (u & 0x80000000u) ? (u ^ 0x80000000u) : ~u;
    return __uint_as_float(v);
}

// wave-per-edge: lane = h*32+hl, lane covers channels hl*4..hl*4+3 of head h
__global__ __launch_bounds__(256)
void pass_a(const float* __restrict__ Q, const float* __restrict__ Kb,
            const float* __restrict__ P, const float* __restrict__ EA,
            const int* __restrict__ src, const int* __restrict__ dst,
            float* __restrict__ alpha, unsigned* __restrict__ amax, int E) {
    const int lane = threadIdx.x & 63;
    const int h = lane >> 5, hl = lane & 31;
    const int wid = (blockIdx.x * blockDim.x + threadIdx.x) >> 6;
    const int nw = (gridDim.x * blockDim.x) >> 6;
    const float inv = 0.08838834764831845f;  // 1/sqrt(128)
    for (int e = wid; e < E; e += nw) {
        int s = src[e], d = dst[e];
        float4 qv = *(const float4*)(Q  + (size_t)d*256 + h*128 + hl*4);
        float4 kv = *(const float4*)(Kb + (size_t)s*256 + h*128 + hl*4);
        float part = qv.x*kv.x + qv.y*kv.y + qv.z*kv.z + qv.w*kv.w;
        part += P[(size_t)d*64 + h*32 + hl] * EA[(size_t)e*32 + hl];
        #pragma unroll
        for (int off = 16; off >= 1; off >>= 1) part += __shfl_xor(part, off);
        if (hl == 0) {
            float a = part * inv;
            alpha[(size_t)e*2 + h] = a;
            atomicMax(amax + (size_t)d*2 + h, ord_encode(a));
        }
    }
}

__global__ __launch_bounds__(256)
void pass_b(float* __restrict__ alpha, const int* __restrict__ dst,
            const unsigned* __restrict__ amax, float* __restrict__ den, int E2) {
    int i = blockIdx.x * blockDim.x + threadIdx.x;
    if (i < E2) {
        int e = i >> 1, hh = i & 1;
        int d = dst[e];
        float m = ord_decode(amax[(size_t)d*2 + hh]);
        float ex = expf(alpha[i] - m);
        alpha[i] = ex;
        atomicAdd(den + (size_t)d*2 + hh, ex);
    }
}

__global__ __launch_bounds__(256)
void pass_c(const float* __restrict__ V, const float* __restrict__ ex,
            const float* __restrict__ den, const float* __restrict__ EA,
            const int* __restrict__ src, const int* __restrict__ dst,
            float* __restrict__ agg, float* __restrict__ wea, int E) {
    const int lane = threadIdx.x & 63;
    const int h = lane >> 5, hl = lane & 31;
    const int wid = (blockIdx.x * blockDim.x + threadIdx.x) >> 6;
    const int nw = (gridDim.x * blockDim.x) >> 6;
    for (int e = wid; e < E; e += nw) {
        int s = src[e], d = dst[e];
        float w = ex[(size_t)e*2 + h] / (den[(size_t)d*2 + h] + 1e-16f);
        float4 vv = *(const float4*)(V + (size_t)s*256 + h*128 + hl*4);
        float* ap = agg + (size_t)d*256 + h*128 + hl*4;
        atomicAdd(ap+0, w*vv.x);
        atomicAdd(ap+1, w*vv.y);
        atomicAdd(ap+2, w*vv.z);
        atomicAdd(ap+3, w*vv.w);
        atomicAdd(wea + (size_t)d*64 + h*32 + hl, w * EA[(size_t)e*32 + hl]);
    }
}

// h = LN1(x + 0.5*(agg_h0+agg_h1) + skip); wave per node (block = 4 nodes)
__global__ __launch_bounds__(256)
void node_ln1(const float* __restrict__ x, const float* __restrict__ agg,
              const float* __restrict__ skip, const float* __restrict__ g,
              const float* __restrict__ b, float* __restrict__ hout, int N) {
    int node = blockIdx.x * 4 + (threadIdx.x >> 6);
    if (node >= N) return;
    int lane = threadIdx.x & 63;
    float2 xv = ((const float2*)(x    + (size_t)node*128))[lane];
    float2 a0 = ((const float2*)(agg  + (size_t)node*256))[lane];
    float2 a1 = ((const float2*)(agg  + (size_t)node*256 + 128))[lane];
    float2 sv = ((const float2*)(skip + (size_t)node*128))[lane];
    float t0 = xv.x + 0.5f*(a0.x + a1.x) + sv.x;
    float t1 = xv.y + 0.5f*(a0.y + a1.y) + sv.y;
    float s = t0 + t1;
    #pragma unroll
    for (int off = 32; off >= 1; off >>= 1) s += __shfl_xor(s, off);
    float mu = s * (1.f/128.f);
    float d0 = t0 - mu, d1 = t1 - mu;
    float q = d0*d0 + d1*d1;
    #pragma unroll
    for (int off = 32; off >= 1; off >>= 1) q += __shfl_xor(q, off);
    float rs = rsqrtf(q * (1.f/128.f) + 1e-5f);
    float2 gv = ((const float2*)g)[lane], bv = ((const float2*)b)[lane];
    float2 o;
    o.x = d0*rs*gv.x + bv.x;
    o.y = d1*rs*gv.y + bv.y;
    ((float2*)(hout + (size_t)node*128))[lane] = o;
}

// out = LN2(h + f)
__global__ __launch_bounds__(256)
void node_ln2(const float* __restrict__ hbuf, const float* __restrict__ f,
              const float* __restrict__ g, const float* __restrict__ b,
              float* __restrict__ out, int N) {
    int node = blockIdx.x * 4 + (threadIdx.x >> 6);
    if (node >= N) return;
    int lane = threadIdx.x & 63;
    float2 hv = ((const float2*)(hbuf + (size_t)node*128))[lane];
    float2 fv = ((const float2*)(f    + (size_t)node*128))[lane];
    float t0 = hv.x + fv.x;
    float t1 = hv.y + fv.y;
    float s = t0 + t1;
    #pragma unroll
    for (int off = 32; off >= 1; off >>= 1) s += __shfl_xor(s, off);
    float mu = s * (1.f/128.f);
    float d0 = t0 - mu, d1 = t1 - mu;
    float q = d0*d0 + d1*d1;
    #pragma unroll
    for (int off = 32; off >= 1; off >>= 1) q += __shfl_xor(q, off);
    float rs = rsqrtf(q * (1.f/128.f) + 1e-5f);
    float2 gv = ((const float2*)g)[lane], bv = ((const float2*)b)[lane];
    float2 o;
    o.x = d0*rs*gv.x + bv.x;
    o.y = d1*rs*gv.y + bv.y;
    ((float2*)(out + (size_t)node*128))[lane] = o;
}

extern "C" void kernel_launch(void* const* d_in, const int* in_sizes, int n_in,
                              void* d_out, int out_size, void* d_ws, size_t ws_size,
                              hipStream_t stream) {
    const float* x    = (const float*)d_in[0];
    const int*   ei   = (const int*)d_in[1];
    const float* ea   = (const float*)d_in[2];
    const float* Wq   = (const float*)d_in[3];
    const float* bq   = (const float*)d_in[4];
    const float* Wk   = (const float*)d_in[5];
    const float* bk   = (const float*)d_in[6];
    const float* Wv   = (const float*)d_in[7];
    const float* bv   = (const float*)d_in[8];
    const float* We   = (const float*)d_in[9];
    const float* Wsk  = (const float*)d_in[10];
    const float* bsk  = (const float*)d_in[11];
    const float* g1   = (const float*)d_in[12];
    const float* b1l  = (const float*)d_in[13];
    const float* W1   = (const float*)d_in[14];
    const float* b1f  = (const float*)d_in[15];
    const float* W2   = (const float*)d_in[16];
    const float* b2f  = (const float*)d_in[17];
    const float* g2   = (const float*)d_in[18];
    const float* b2l  = (const float*)d_in[19];
    float* out = (float*)d_out;

    const int N = in_sizes[0] / 128;
    const int E = in_sizes[2] / 32;
    const int* src = ei;
    const int* dst = ei + E;

    float* ws = (float*)d_ws;
    float* Qb  = ws;                        // [N,256] q     (later: agg)
    float* Kb  = ws + (size_t)N*256;        // [N,256] k     (later: ffn mid)
    float* Vb  = ws + (size_t)N*512;        // [N,256] v     (later: ffn out f)
    float* Sb  = ws + (size_t)N*768;        // [N,128] skip  (later: h)
    float* alp = ws + (size_t)N*896;        // [E,2] alpha -> ex
    unsigned* amax = (unsigned*)(alp + (size_t)E*2);   // [N,2] ordered-uint max
    float* den = (float*)amax + (size_t)N*2;           // [N,2]
    float* Pb  = den + (size_t)N*2;         // [N,2,32] P    (later: wea)
    float* WeT = Pb + (size_t)N*64;         // [2,32,128]

    const int gy = (N + 63) / 64;

    // q, k, v, skip projections
    gemm_tn<0,0><<<dim3(4, gy), 256, 0, stream>>>(x, 128, Wq, 128, bq, Qb, 256, N, 128, 256);
    gemm_tn<0,0><<<dim3(4, gy), 256, 0, stream>>>(x, 128, Wk, 128, bk, Kb, 256, N, 128, 256);
    gemm_tn<0,0><<<dim3(4, gy), 256, 0, stream>>>(x, 128, Wv, 128, bv, Vb, 256, N, 128, 256);
    gemm_tn<0,0><<<dim3(2, gy), 256, 0, stream>>>(x, 128, Wsk, 128, bsk, Sb, 128, N, 128, 128);

    // We^T staging, then P = q_h @ We_h  ([N,128] @ [128,32])
    transpose_we<<<32, 256, 0, stream>>>(We, WeT);
    gemm_tn<0,0><<<dim3(1, gy), 256, 0, stream>>>(Qb,       256, WeT,        128, nullptr, Pb,      64, N, 128, 32);
    gemm_tn<0,0><<<dim3(1, gy), 256, 0, stream>>>(Qb + 128, 256, WeT + 4096, 128, nullptr, Pb + 32, 64, N, 128, 32);

    // softmax state init
    init_nd<<<(2*N + 255)/256, 256, 0, stream>>>(amax, den, 2*N);

    // pass A: alpha + segment max
    pass_a<<<2048, 256, 0, stream>>>(Qb, Kb, Pb, ea, src, dst, alp, amax, E);

    // zero agg (aliases Qb) and wea (aliases Pb) — only now that A is done with them
    zero_f<<<((int)(N*256) + 255)/256, 256, 0, stream>>>(Qb, N*256);
    zero_f<<<((int)(N*64) + 255)/256, 256, 0, stream>>>(Pb, N*64);

    // pass B: ex + denom
    pass_b<<<(2*E + 255)/256, 256, 0, stream>>>(alp, dst, amax, den, 2*E);

    // pass C: weighted aggregation (v part + wea)
    pass_c<<<2048, 256, 0, stream>>>(Vb, alp, den, ea, src, dst, Qb, Pb, E);

    // e-contribution: agg[:,h,:] += wea[:,h,:] @ We_h^T  ([N,32] @ [128,32]^T)
    gemm_tn<0,1><<<dim3(2, gy), 256, 0, stream>>>(Pb,      64, We,            32, nullptr, Qb,       256, N, 32, 128);
    gemm_tn<0,1><<<dim3(2, gy), 256, 0, stream>>>(Pb + 32, 64, We + 128*32,   32, nullptr, Qb + 128, 256, N, 32, 128);

    // h = LN1(x + mean_heads(agg) + skip)   (writes h over Sb)
    node_ln1<<<(N + 3)/4, 256, 0, stream>>>(x, Qb, Sb, g1, b1l, Sb, N);

    // FFN
    gemm_tn<1,0><<<dim3(4, gy), 256, 0, stream>>>(Sb, 128, W1, 128, b1f, Kb, 256, N, 128, 256);
    gemm_tn<0,0><<<dim3(2, gy), 256, 0, stream>>>(Kb, 256, W2, 256, b2f, Vb, 128, N, 256, 128);

    // out = LN2(h + f)
    node_ln2<<<(N + 3)/4, 256, 0, stream>>>(Sb, Vb, g2, b2l, out, N);
}

// Round 2
// 770.303 us; speedup vs baseline: 2.8082x; 2.8082x over previous
//
#include <hip/hip_runtime.h>
#include <hip/hip_bf16.h>

// ---------------------------------------------------------------------------
// GraphTransformerBlock: TransformerConv(H=2, C=128) + skip + LN + FFN + LN
// R2: replace atomic scatter (pass_a/b/c, 128M fp32 atomics, 1.7GB HBM writes)
// with device-built dst-CSR + fused wave-per-node online-softmax aggregation.
//   q,k,v,skip : fp32 tiled GEMMs
//   P = q @ We_h            (alpha needs no per-edge e projection)
//   CSR build  : degree count -> hierarchical scan -> fill (int atomics only)
//   fused_attn : per dst node, online softmax over incident edges;
//                agg[d] = sum w*v[s], wea[d] = sum w*ea[e]; plain stores
//   econ       : agg[:,h,:] += wea[:,h,:] @ We_h^T  (e-projection at nodes)
//   node       : h = LN1(x + mean_heads(agg) + skip); FFN; out = LN2(h+f)
// ---------------------------------------------------------------------------

#define TILE_BK 16

template<int ACT, int ADD>
__global__ __launch_bounds__(256)
void gemm_tn(const float* __restrict__ A, int lda,
             const float* __restrict__ W, int ldw,
             const float* __restrict__ bias,
             float* __restrict__ out, int ldo,
             int M, int K, int OC) {
    // C[M,OC] = act(A[M,K] @ W[OC,K]^T + bias), optional +=
    __shared__ float As[TILE_BK][68];
    __shared__ float Ws[TILE_BK][68];
    const int tid = threadIdx.x;
    const int tx = tid & 15, ty = tid >> 4;
    const int row0 = blockIdx.y * 64, col0 = blockIdx.x * 64;
    const int lr = tid >> 2, lc = (tid & 3) * 4;
    const int gr = row0 + lr;
    const int gc = col0 + lr;
    const float* aBase = A + (size_t)gr * lda + lc;
    const float* wBase = W + (size_t)gc * ldw + lc;
    const bool aOk = (gr < M);
    const bool wOk = (gc < OC);
    float acc[4][4] = {{0.f}};
    for (int kt = 0; kt < K; kt += TILE_BK) {
        float4 av = aOk ? *(const float4*)(aBase + kt) : make_float4(0.f,0.f,0.f,0.f);
        float4 wv = wOk ? *(const float4*)(wBase + kt) : make_float4(0.f,0.f,0.f,0.f);
        __syncthreads();
        As[lc+0][lr] = av.x; As[lc+1][lr] = av.y; As[lc+2][lr] = av.z; As[lc+3][lr] = av.w;
        Ws[lc+0][lr] = wv.x; Ws[lc+1][lr] = wv.y; Ws[lc+2][lr] = wv.z; Ws[lc+3][lr] = wv.w;
        __syncthreads();
        #pragma unroll
        for (int kk = 0; kk < TILE_BK; kk++) {
            float4 a = *(const float4*)&As[kk][ty*4];
            float4 b = *(const float4*)&Ws[kk][tx*4];
            acc[0][0] += a.x*b.x; acc[0][1] += a.x*b.y; acc[0][2] += a.x*b.z; acc[0][3] += a.x*b.w;
            acc[1][0] += a.y*b.x; acc[1][1] += a.y*b.y; acc[1][2] += a.y*b.z; acc[1][3] += a.y*b.w;
            acc[2][0] += a.z*b.x; acc[2][1] += a.z*b.y; acc[2][2] += a.z*b.z; acc[2][3] += a.z*b.w;
            acc[3][0] += a.w*b.x; acc[3][1] += a.w*b.y; acc[3][2] += a.w*b.z; acc[3][3] += a.w*b.w;
        }
    }
    #pragma unroll
    for (int i = 0; i < 4; i++) {
        int r = row0 + ty*4 + i;
        if (r >= M) continue;
        #pragma unroll
        for (int j = 0; j < 4; j++) {
            int c = col0 + tx*4 + j;
            if (c >= OC) continue;
            float v = acc[i][j] + (bias ? bias[c] : 0.f);
            if (ACT == 1) v = (v > 0.f) ? v : 0.01f * v;
            if (ADD) out[(size_t)r*ldo + c] += v;
            else     out[(size_t)r*ldo + c]  = v;
        }
    }
}

__global__ void transpose_we(const float* __restrict__ We, float* __restrict__ WeT) {
    int i = blockIdx.x * blockDim.x + threadIdx.x;   // 2*32*128 = 8192
    if (i < 8192) {
        int h = i >> 12, rem = i & 4095, t = rem >> 7, c = rem & 127;
        WeT[i] = We[(size_t)(h*128 + c) * 32 + t];
    }
}

__global__ void zero_int(int* __restrict__ p, int n) {
    int i = blockIdx.x * blockDim.x + threadIdx.x;
    if (i < n) p[i] = 0;
}

__global__ void deg_count(const int* __restrict__ dst, int* __restrict__ deg, int E) {
    int e = blockIdx.x * blockDim.x + threadIdx.x;
    if (e < E) atomicAdd(&deg[dst[e]], 1);
}

// per-block inclusive scan of deg (256/block); tmp = inclusive scan, bsum = block total
__global__ __launch_bounds__(256)
void scan_block(const int* __restrict__ deg, int* __restrict__ tmp,
                int* __restrict__ bsum, int n) {
    __shared__ int lds[256];
    int i = blockIdx.x * 256 + threadIdx.x;
    int v = (i < n) ? deg[i] : 0;
    lds[threadIdx.x] = v;
    __syncthreads();
    #pragma unroll
    for (int off = 1; off < 256; off <<= 1) {
        int t = (threadIdx.x >= off) ? lds[threadIdx.x - off] : 0;
        __syncthreads();
        lds[threadIdx.x] += t;
        __syncthreads();
    }
    if (i < n) tmp[i] = lds[threadIdx.x];
    if (threadIdx.x == 255) bsum[blockIdx.x] = lds[255];
}

// single block: exclusive scan of bsum (nb <= 1024)
__global__ __launch_bounds__(1024)
void scan_bsum(int* __restrict__ bsum, int nb) {
    __shared__ int lds[1024];
    int v = (threadIdx.x < nb) ? bsum[threadIdx.x] : 0;
    lds[threadIdx.x] = v;
    __syncthreads();
    #pragma unroll
    for (int off = 1; off < 1024; off <<= 1) {
        int t = (threadIdx.x >= off) ? lds[threadIdx.x - off] : 0;
        __syncthreads();
        lds[threadIdx.x] += t;
        __syncthreads();
    }
    if (threadIdx.x < nb) bsum[threadIdx.x] = lds[threadIdx.x] - v;  // exclusive
}

// row[i+1] = tmp[i] + bsum_excl[block]; row[0] = 0
__global__ __launch_bounds__(256)
void scan_finalize(const int* __restrict__ tmp, const int* __restrict__ bsum,
                   int* __restrict__ row, int n) {
    int i = blockIdx.x * 256 + threadIdx.x;
    if (i < n) row[i + 1] = tmp[i] + bsum[blockIdx.x];
    if (i == 0) row[0] = 0;
}

__global__ void csr_fill(const int* __restrict__ dst, const int* __restrict__ row,
                         int* __restrict__ cnt, int* __restrict__ eid, int E) {
    int e = blockIdx.x * blockDim.x + threadIdx.x;
    if (e < E) {
        int d = dst[e];
        int pos = row[d] + atomicAdd(&cnt[d], 1);
        eid[pos] = e;
    }
}

// one wave per dst node: online-softmax attention over its incident edges.
// lane = h*32+hl; lane covers v-channels hl*4..hl*4+3 of head h, wea channel hl.
__global__ __launch_bounds__(256)
void fused_attn(const float* __restrict__ Q, const float* __restrict__ K,
                const float* __restrict__ V, const float* __restrict__ P,
                const float* __restrict__ EA, const int* __restrict__ src,
                const int* __restrict__ row, const int* __restrict__ eid,
                float* __restrict__ agg, float* __restrict__ wea, int N) {
    int node = blockIdx.x * 4 + (threadIdx.x >> 6);
    if (node >= N) return;
    const int lane = threadIdx.x & 63;
    const int h = lane >> 5, hl = lane & 31;
    const float inv = 0.08838834764831845f;  // 1/sqrt(128)

    float4 qv = *(const float4*)(Q + (size_t)node*256 + h*128 + hl*4);
    float pd = P[(size_t)node*64 + lane];

    int j = row[node], jend = row[node + 1];
    float m = -INFINITY, l = 0.f, wacc = 0.f;
    float4 acc = make_float4(0.f, 0.f, 0.f, 0.f);

    float4 kv_n = make_float4(0,0,0,0), vv_n = make_float4(0,0,0,0);
    float ea_n = 0.f;
    if (j < jend) {
        int e = eid[j], s = src[e];
        kv_n = *(const float4*)(K + (size_t)s*256 + h*128 + hl*4);
        vv_n = *(const float4*)(V + (size_t)s*256 + h*128 + hl*4);
        ea_n = EA[(size_t)e*32 + hl];
    }
    while (j < jend) {
        float4 kv = kv_n, vv = vv_n;
        float eav = ea_n;
        j++;
        if (j < jend) {                       // prefetch next edge before the reduce chain
            int e = eid[j], s = src[e];
            kv_n = *(const float4*)(K + (size_t)s*256 + h*128 + hl*4);
            vv_n = *(const float4*)(V + (size_t)s*256 + h*128 + hl*4);
            ea_n = EA[(size_t)e*32 + hl];
        }
        float part = qv.x*kv.x + qv.y*kv.y + qv.z*kv.z + qv.w*kv.w + pd*eav;
        #pragma unroll
        for (int off = 16; off >= 1; off >>= 1) part += __shfl_xor(part, off);
        float a = part * inv;
        float mn = fmaxf(m, a);
        float scale = __expf(m - mn);         // m=-inf first iter -> 0
        float w = __expf(a - mn);
        l = l * scale + w;
        acc.x = acc.x * scale + w * vv.x;
        acc.y = acc.y * scale + w * vv.y;
        acc.z = acc.z * scale + w * vv.z;
        acc.w = acc.w * scale + w * vv.w;
        wacc = wacc * scale + w * eav;
        m = mn;
    }
    float r = 1.f / (l + 1e-16f);
    acc.x *= r; acc.y *= r; acc.z *= r; acc.w *= r;
    *(float4*)(agg + (size_t)node*256 + h*128 + hl*4) = acc;
    wea[(size_t)node*64 + lane] = wacc * r;
}

// h = LN1(x + 0.5*(agg_h0+agg_h1) + skip); wave per node
__global__ __launch_bounds__(256)
void node_ln1(const float* __restrict__ x, const float* __restrict__ agg,
              const float* __restrict__ skip, const float* __restrict__ g,
              const float* __restrict__ b, float* __restrict__ hout, int N) {
    int node = blockIdx.x * 4 + (threadIdx.x >> 6);
    if (node >= N) return;
    int lane = threadIdx.x & 63;
    float2 xv = ((const float2*)(x    + (size_t)node*128))[lane];
    float2 a0 = ((const float2*)(agg  + (size_t)node*256))[lane];
    float2 a1 = ((const float2*)(agg  + (size_t)node*256 + 128))[lane];
    float2 sv = ((const float2*)(skip + (size_t)node*128))[lane];
    float t0 = xv.x + 0.5f*(a0.x + a1.x) + sv.x;
    float t1 = xv.y + 0.5f*(a0.y + a1.y) + sv.y;
    float s = t0 + t1;
    #pragma unroll
    for (int off = 32; off >= 1; off >>= 1) s += __shfl_xor(s, off);
    float mu = s * (1.f/128.f);
    float d0 = t0 - mu, d1 = t1 - mu;
    float q = d0*d0 + d1*d1;
    #pragma unroll
    for (int off = 32; off >= 1; off >>= 1) q += __shfl_xor(q, off);
    float rs = rsqrtf(q * (1.f/128.f) + 1e-5f);
    float2 gv = ((const float2*)g)[lane], bv = ((const float2*)b)[lane];
    float2 o;
    o.x = d0*rs*gv.x + bv.x;
    o.y = d1*rs*gv.y + bv.y;
    ((float2*)(hout + (size_t)node*128))[lane] = o;
}

// out = LN2(h + f)
__global__ __launch_bounds__(256)
void node_ln2(const float* __restrict__ hbuf, const float* __restrict__ f,
              const float* __restrict__ g, const float* __restrict__ b,
              float* __restrict__ out, int N) {
    int node = blockIdx.x * 4 + (threadIdx.x >> 6);
    if (node >= N) return;
    int lane = threadIdx.x & 63;
    float2 hv = ((const float2*)(hbuf + (size_t)node*128))[lane];
    float2 fv = ((const float2*)(f    + (size_t)node*128))[lane];
    float t0 = hv.x + fv.x;
    float t1 = hv.y + fv.y;
    float s = t0 + t1;
    #pragma unroll
    for (int off = 32; off >= 1; off >>= 1) s += __shfl_xor(s, off);
    float mu = s * (1.f/128.f);
    float d0 = t0 - mu, d1 = t1 - mu;
    float q = d0*d0 + d1*d1;
    #pragma unroll
    for (int off = 32; off >= 1; off >>= 1) q += __shfl_xor(q, off);
    float rs = rsqrtf(q * (1.f/128.f) + 1e-5f);
    float2 gv = ((const float2*)g)[lane], bv = ((const float2*)b)[lane];
    float2 o;
    o.x = d0*rs*gv.x + bv.x;
    o.y = d1*rs*gv.y + bv.y;
    ((float2*)(out + (size_t)node*128))[lane] = o;
}

extern "C" void kernel_launch(void* const* d_in, const int* in_sizes, int n_in,
                              void* d_out, int out_size, void* d_ws, size_t ws_size,
                              hipStream_t stream) {
    const float* x    = (const float*)d_in[0];
    const int*   ei   = (const int*)d_in[1];
    const float* ea   = (const float*)d_in[2];
    const float* Wq   = (const float*)d_in[3];
    const float* bq   = (const float*)d_in[4];
    const float* Wk   = (const float*)d_in[5];
    const float* bk   = (const float*)d_in[6];
    const float* Wv   = (const float*)d_in[7];
    const float* bv   = (const float*)d_in[8];
    const float* We   = (const float*)d_in[9];
    const float* Wsk  = (const float*)d_in[10];
    const float* bsk  = (const float*)d_in[11];
    const float* g1   = (const float*)d_in[12];
    const float* b1l  = (const float*)d_in[13];
    const float* W1   = (const float*)d_in[14];
    const float* b1f  = (const float*)d_in[15];
    const float* W2   = (const float*)d_in[16];
    const float* b2f  = (const float*)d_in[17];
    const float* g2   = (const float*)d_in[18];
    const float* b2l  = (const float*)d_in[19];
    float* out = (float*)d_out;

    const int N = in_sizes[0] / 128;
    const int E = in_sizes[2] / 32;
    const int* src = ei;
    const int* dst = ei + E;

    float* ws = (float*)d_ws;
    float* Qb  = ws;                        // [N,256] q     (later: agg)
    float* Kb  = ws + (size_t)N*256;        // [N,256] k     (later: ffn mid)
    float* Vb  = ws + (size_t)N*512;        // [N,256] v     (later: ffn out f)
    float* Sb  = ws + (size_t)N*768;        // [N,128] skip  (later: h)
    float* Pb  = ws + (size_t)N*896;        // [N,2,32] P    (later: wea)
    float* WeT = Pb + (size_t)N*64;         // [2,32,128]
    int* deg   = (int*)(WeT + 8192);        // [N]
    int* cnt   = deg + N;                   // [N]
    int* tmp   = cnt + N;                   // [N]
    int* rowp  = tmp + N;                   // [N+1]
    int* bsum  = rowp + N + 1;              // [<=1024]
    int* eid   = bsum + 1024;               // [E]

    const int gy = (N + 63) / 64;
    const int nb = (N + 255) / 256;

    // q, k, v, skip projections
    gemm_tn<0,0><<<dim3(4, gy), 256, 0, stream>>>(x, 128, Wq, 128, bq, Qb, 256, N, 128, 256);
    gemm_tn<0,0><<<dim3(4, gy), 256, 0, stream>>>(x, 128, Wk, 128, bk, Kb, 256, N, 128, 256);
    gemm_tn<0,0><<<dim3(4, gy), 256, 0, stream>>>(x, 128, Wv, 128, bv, Vb, 256, N, 128, 256);
    gemm_tn<0,0><<<dim3(2, gy), 256, 0, stream>>>(x, 128, Wsk, 128, bsk, Sb, 128, N, 128, 128);

    // We^T staging, then P = q_h @ We_h  ([N,128] @ [128,32])
    transpose_we<<<32, 256, 0, stream>>>(We, WeT);
    gemm_tn<0,0><<<dim3(1, gy), 256, 0, stream>>>(Qb,       256, WeT,        128, nullptr, Pb,      64, N, 128, 32);
    gemm_tn<0,0><<<dim3(1, gy), 256, 0, stream>>>(Qb + 128, 256, WeT + 4096, 128, nullptr, Pb + 32, 64, N, 128, 32);

    // CSR build (dst-sorted edge ids)
    zero_int<<<(2*N + 255)/256, 256, 0, stream>>>(deg, 2*N);   // deg + cnt
    deg_count<<<(E + 255)/256, 256, 0, stream>>>(dst, deg, E);
    scan_block<<<nb, 256, 0, stream>>>(deg, tmp, bsum, N);
    scan_bsum<<<1, 1024, 0, stream>>>(bsum, nb);
    scan_finalize<<<nb, 256, 0, stream>>>(tmp, bsum, rowp, N);
    csr_fill<<<(E + 255)/256, 256, 0, stream>>>(dst, rowp, cnt, eid, E);

    // fused online-softmax attention: agg (aliases Qb), wea (aliases Pb)
    fused_attn<<<(N + 3)/4, 256, 0, stream>>>(Qb, Kb, Vb, Pb, ea, src, rowp, eid, Qb, Pb, N);

    // e-contribution: agg[:,h,:] += wea[:,h,:] @ We_h^T  ([N,32] @ [128,32]^T)
    gemm_tn<0,1><<<dim3(2, gy), 256, 0, stream>>>(Pb,      64, We,          32, nullptr, Qb,       256, N, 32, 128);
    gemm_tn<0,1><<<dim3(2, gy), 256, 0, stream>>>(Pb + 32, 64, We + 128*32, 32, nullptr, Qb + 128, 256, N, 32, 128);

    // h = LN1(x + mean_heads(agg) + skip)   (writes h over Sb)
    node_ln1<<<(N + 3)/4, 256, 0, stream>>>(x, Qb, Sb, g1, b1l, Sb, N);

    // FFN
    gemm_tn<1,0><<<dim3(4, gy), 256, 0, stream>>>(Sb, 128, W1, 128, b1f, Kb, 256, N, 128, 256);
    gemm_tn<0,0><<<dim3(2, gy), 256, 0, stream>>>(Kb, 256, W2, 256, b2f, Vb, 128, N, 256, 128);

    // out = LN2(h + f)
    node_ln2<<<(N + 3)/4, 256, 0, stream>>>(Sb, Vb, g2, b2l, out, N);
}

// Round 3
// 489.898 us; speedup vs baseline: 4.4156x; 1.5724x over previous
//
#include <hip/hip_runtime.h>
#include <hip/hip_bf16.h>

// ---------------------------------------------------------------------------
// GraphTransformerBlock: TransformerConv(H=2, C=128) + skip + LN + FFN + LN
// R3: all dense GEMMs -> bf16 MFMA (16x16x32, 128x128 tile); single fused
// projection GEMM x@[Wq|Wk|Wv|Wskip|Wcomb]^T -> OUT1 bf16 [N,1024];
// fused_attn gathers bf16 K/V (half the bytes); FFN via MFMA; CSR unchanged.
//   Wcomb_h = Wq_h^T @ We_h  folds P = q_h@We_h into the projection GEMM.
// ---------------------------------------------------------------------------

typedef __attribute__((ext_vector_type(8))) short bf16x8;
typedef __attribute__((ext_vector_type(4))) float f32x4;

__device__ __forceinline__ float bf2f(unsigned short u) {
    union { float f; unsigned u32; } x; x.u32 = ((unsigned)u) << 16; return x.f;
}
__device__ __forceinline__ unsigned short f2bf(float f) {
    unsigned u = __float_as_uint(f);
    return (unsigned short)((u + 0x7FFFu + ((u >> 16) & 1u)) >> 16);
}

// ---------------- bf16 MFMA GEMM: C[M,OC] = act(A[M,K] @ W[OC,K]^T + bias) --
// 128x128 tile, BK=32, 4 waves; OC = gridDim.x*128 (exact), M guarded.
template<int ACT, int OUT_BF16>
__global__ __launch_bounds__(256)
void gemm_mfma(const unsigned short* __restrict__ A, int lda,
               const unsigned short* __restrict__ W, int ldw,
               const float* __restrict__ bias,
               void* __restrict__ outp, int ldo, int M, int K) {
    __shared__ unsigned short As[128 * 40];   // pitch 40 elems (80B) kills conflicts
    __shared__ unsigned short Bs[128 * 40];
    const int tid = threadIdx.x;
    const int wave = tid >> 6, lane = tid & 63;
    const int row0 = blockIdx.y * 128, col0 = blockIdx.x * 128;
    const int srow = tid >> 2;        // 0..63
    const int skg  = (tid & 3) * 8;   // k element offset of 16B chunk
    int r0 = row0 + srow;      if (r0 >= M) r0 = 0;
    int r1 = row0 + srow + 64; if (r1 >= M) r1 = 0;
    const int b0 = col0 + srow, b1 = col0 + srow + 64;

    f32x4 acc[2][8];
    const f32x4 z4 = {0.f, 0.f, 0.f, 0.f};
    #pragma unroll
    for (int i = 0; i < 2; i++)
        #pragma unroll
        for (int j = 0; j < 8; j++) acc[i][j] = z4;

    const int mrow = wave * 32 + (lane & 15);
    const int kq = (lane >> 4) * 8;

    for (int kt = 0; kt < K; kt += 32) {
        float4 a0 = *(const float4*)(A + (size_t)r0 * lda + kt + skg);
        float4 a1 = *(const float4*)(A + (size_t)r1 * lda + kt + skg);
        float4 w0 = *(const float4*)(W + (size_t)b0 * ldw + kt + skg);
        float4 w1 = *(const float4*)(W + (size_t)b1 * ldw + kt + skg);
        __syncthreads();
        *(float4*)&As[srow * 40 + skg]        = a0;
        *(float4*)&As[(srow + 64) * 40 + skg] = a1;
        *(float4*)&Bs[srow * 40 + skg]        = w0;
        *(float4*)&Bs[(srow + 64) * 40 + skg] = w1;
        __syncthreads();
        bf16x8 af0 = *(const bf16x8*)&As[mrow * 40 + kq];
        bf16x8 af1 = *(const bf16x8*)&As[(mrow + 16) * 40 + kq];
        bf16x8 bfr[8];
        #pragma unroll
        for (int j = 0; j < 8; j++)
            bfr[j] = *(const bf16x8*)&Bs[(j * 16 + (lane & 15)) * 40 + kq];
        #pragma unroll
        for (int j = 0; j < 8; j++) {
            acc[0][j] = __builtin_amdgcn_mfma_f32_16x16x32_bf16(af0, bfr[j], acc[0][j], 0, 0, 0);
            acc[1][j] = __builtin_amdgcn_mfma_f32_16x16x32_bf16(af1, bfr[j], acc[1][j], 0, 0, 0);
        }
    }

    // C/D layout: col = lane&15, row = (lane>>4)*4 + reg   [m89/m91 verified]
    const int orow0 = row0 + wave * 32 + ((lane >> 4) << 2);
    const int ocol0 = col0 + (lane & 15);
    #pragma unroll
    for (int i = 0; i < 2; i++) {
        #pragma unroll
        for (int r = 0; r < 4; r++) {
            int row = orow0 + i * 16 + r;
            if (row >= M) continue;
            #pragma unroll
            for (int j = 0; j < 8; j++) {
                int col = ocol0 + j * 16;
                float v = acc[i][j][r] + bias[col];
                if (ACT == 1) v = (v > 0.f) ? v : 0.01f * v;
                if (OUT_BF16) ((unsigned short*)outp)[(size_t)row * ldo + col] = f2bf(v);
                else          ((float*)outp)[(size_t)row * ldo + col] = v;
            }
        }
    }
}

// ---------------- fp32 vector GEMM (small econ GEMMs only) ------------------
#define TILE_BK 16
template<int ACT, int ADD>
__global__ __launch_bounds__(256)
void gemm_tn(const float* __restrict__ A, int lda,
             const float* __restrict__ W, int ldw,
             const float* __restrict__ bias,
             float* __restrict__ out, int ldo,
             int M, int K, int OC) {
    __shared__ float As[TILE_BK][68];
    __shared__ float Ws[TILE_BK][68];
    const int tid = threadIdx.x;
    const int tx = tid & 15, ty = tid >> 4;
    const int row0 = blockIdx.y * 64, col0 = blockIdx.x * 64;
    const int lr = tid >> 2, lc = (tid & 3) * 4;
    const int gr = row0 + lr;
    const int gc = col0 + lr;
    const float* aBase = A + (size_t)gr * lda + lc;
    const float* wBase = W + (size_t)gc * ldw + lc;
    const bool aOk = (gr < M);
    const bool wOk = (gc < OC);
    float acc[4][4] = {{0.f}};
    for (int kt = 0; kt < K; kt += TILE_BK) {
        float4 av = aOk ? *(const float4*)(aBase + kt) : make_float4(0.f,0.f,0.f,0.f);
        float4 wv = wOk ? *(const float4*)(wBase + kt) : make_float4(0.f,0.f,0.f,0.f);
        __syncthreads();
        As[lc+0][lr] = av.x; As[lc+1][lr] = av.y; As[lc+2][lr] = av.z; As[lc+3][lr] = av.w;
        Ws[lc+0][lr] = wv.x; Ws[lc+1][lr] = wv.y; Ws[lc+2][lr] = wv.z; Ws[lc+3][lr] = wv.w;
        __syncthreads();
        #pragma unroll
        for (int kk = 0; kk < TILE_BK; kk++) {
            float4 a = *(const float4*)&As[kk][ty*4];
            float4 b = *(const float4*)&Ws[kk][tx*4];
            acc[0][0] += a.x*b.x; acc[0][1] += a.x*b.y; acc[0][2] += a.x*b.z; acc[0][3] += a.x*b.w;
            acc[1][0] += a.y*b.x; acc[1][1] += a.y*b.y; acc[1][2] += a.y*b.z; acc[1][3] += a.y*b.w;
            acc[2][0] += a.z*b.x; acc[2][1] += a.z*b.y; acc[2][2] += a.z*b.z; acc[2][3] += a.z*b.w;
            acc[3][0] += a.w*b.x; acc[3][1] += a.w*b.y; acc[3][2] += a.w*b.z; acc[3][3] += a.w*b.w;
        }
    }
    #pragma unroll
    for (int i = 0; i < 4; i++) {
        int r = row0 + ty*4 + i;
        if (r >= M) continue;
        #pragma unroll
        for (int j = 0; j < 4; j++) {
            int c = col0 + tx*4 + j;
            if (c >= OC) continue;
            float v = acc[i][j] + (bias ? bias[c] : 0.f);
            if (ACT == 1) v = (v > 0.f) ? v : 0.01f * v;
            if (ADD) out[(size_t)r*ldo + c] += v;
            else     out[(size_t)r*ldo + c]  = v;
        }
    }
}

// ---------------- weight prep ----------------------------------------------
__global__ void f32_to_bf16(const float* __restrict__ in, unsigned short* __restrict__ out, int n) {
    int i = blockIdx.x * blockDim.x + threadIdx.x;
    if (i < n) out[i] = f2bf(in[i]);
}

// wcb[0:8192]  = Wcomb[r][h*32+t] = sum_c Wq[h*128+c][r] * We[h*128+c][t]
// wcb[8192:+64]= bP[h*32+t]       = sum_c bq[h*128+c]    * We[h*128+c][t]
__global__ void wcomb_k(const float* __restrict__ Wq, const float* __restrict__ bq,
                        const float* __restrict__ We, float* __restrict__ wcb) {
    int idx = blockIdx.x * 256 + threadIdx.x;
    if (idx < 8192) {
        int r = idx >> 6, q = idx & 63, h = q >> 5, t = q & 31;
        float s = 0.f;
        for (int c = 0; c < 128; c++)
            s += Wq[(size_t)(h*128 + c) * 128 + r] * We[(size_t)(h*128 + c) * 32 + t];
        wcb[(size_t)r * 64 + q] = s;
    } else if (idx < 8256) {
        int q = idx - 8192, h = q >> 5, t = q & 31;
        float s = 0.f;
        for (int c = 0; c < 128; c++)
            s += bq[h*128 + c] * We[(size_t)(h*128 + c) * 32 + t];
        wcb[8192 + q] = s;
    }
}

// Wcat[1024][128]: rows 0-255 Wq | 256-511 Wk | 512-767 Wv | 768-895 Wskip |
//                  896-959 Wcomb^T | 960-1023 zero
__global__ void pack_wcat(const float* __restrict__ Wq, const float* __restrict__ Wk,
                          const float* __restrict__ Wv, const float* __restrict__ Wsk,
                          const float* __restrict__ wcb, unsigned short* __restrict__ Wcat) {
    int i = blockIdx.x * 256 + threadIdx.x;
    if (i >= 1024 * 128) return;
    int oc = i >> 7, r = i & 127;
    float v;
    if      (oc < 256) v = Wq[i];
    else if (oc < 512) v = Wk[i - 256*128];
    else if (oc < 768) v = Wv[i - 512*128];
    else if (oc < 896) v = Wsk[i - 768*128];
    else if (oc < 960) v = wcb[(size_t)r * 64 + (oc - 896)];
    else v = 0.f;
    Wcat[i] = f2bf(v);
}

__global__ void pack_bcat(const float* __restrict__ bq, const float* __restrict__ bk,
                          const float* __restrict__ bv, const float* __restrict__ bsk,
                          const float* __restrict__ wcb, float* __restrict__ bcat) {
    int oc = blockIdx.x * 256 + threadIdx.x;
    if (oc >= 1024) return;
    float v;
    if      (oc < 256) v = bq[oc];
    else if (oc < 512) v = bk[oc - 256];
    else if (oc < 768) v = bv[oc - 512];
    else if (oc < 896) v = bsk[oc - 768];
    else if (oc < 960) v = wcb[8192 + oc - 896];
    else v = 0.f;
    bcat[oc] = v;
}

// ---------------- CSR build -------------------------------------------------
__global__ void zero_int(int* __restrict__ p, int n) {
    int i = blockIdx.x * blockDim.x + threadIdx.x;
    if (i < n) p[i] = 0;
}
__global__ void deg_count(const int* __restrict__ dst, int* __restrict__ deg, int E) {
    int e = blockIdx.x * blockDim.x + threadIdx.x;
    if (e < E) atomicAdd(&deg[dst[e]], 1);
}
__global__ __launch_bounds__(256)
void scan_block(const int* __restrict__ deg, int* __restrict__ tmp,
                int* __restrict__ bsum, int n) {
    __shared__ int lds[256];
    int i = blockIdx.x * 256 + threadIdx.x;
    int v = (i < n) ? deg[i] : 0;
    lds[threadIdx.x] = v;
    __syncthreads();
    #pragma unroll
    for (int off = 1; off < 256; off <<= 1) {
        int t = (threadIdx.x >= off) ? lds[threadIdx.x - off] : 0;
        __syncthreads();
        lds[threadIdx.x] += t;
        __syncthreads();
    }
    if (i < n) tmp[i] = lds[threadIdx.x];
    if (threadIdx.x == 255) bsum[blockIdx.x] = lds[255];
}
__global__ __launch_bounds__(1024)
void scan_bsum(int* __restrict__ bsum, int nb) {
    __shared__ int lds[1024];
    int v = (threadIdx.x < nb) ? bsum[threadIdx.x] : 0;
    lds[threadIdx.x] = v;
    __syncthreads();
    #pragma unroll
    for (int off = 1; off < 1024; off <<= 1) {
        int t = (threadIdx.x >= off) ? lds[threadIdx.x - off] : 0;
        __syncthreads();
        lds[threadIdx.x] += t;
        __syncthreads();
    }
    if (threadIdx.x < nb) bsum[threadIdx.x] = lds[threadIdx.x] - v;  // exclusive
}
__global__ __launch_bounds__(256)
void scan_finalize(const int* __restrict__ tmp, const int* __restrict__ bsum,
                   int* __restrict__ row, int n) {
    int i = blockIdx.x * 256 + threadIdx.x;
    if (i < n) row[i + 1] = tmp[i] + bsum[blockIdx.x];
    if (i == 0) row[0] = 0;
}
__global__ void csr_fill(const int* __restrict__ dst, const int* __restrict__ row,
                         int* __restrict__ cnt, int* __restrict__ eid, int E) {
    int e = blockIdx.x * blockDim.x + threadIdx.x;
    if (e < E) {
        int d = dst[e];
        int pos = row[d] + atomicAdd(&cnt[d], 1);
        eid[pos] = e;
    }
}

// ---------------- fused online-softmax attention (bf16 gathers) -------------
// OUT1 row [1024]: q 0-255 | k 256-511 | v 512-767 | skip 768-895 | P 896-959
__global__ __launch_bounds__(256)
void fused_attn(const unsigned short* __restrict__ O1, const float* __restrict__ EA,
                const int* __restrict__ src, const int* __restrict__ row,
                const int* __restrict__ eid, float* __restrict__ agg,
                float* __restrict__ wea, int N) {
    int node = blockIdx.x * 4 + (threadIdx.x >> 6);
    if (node >= N) return;
    const int lane = threadIdx.x & 63;
    const int h = lane >> 5, hl = lane & 31;
    const int choff = h * 128 + hl * 4;
    const float inv = 0.08838834764831845f;  // 1/sqrt(128)

    ushort4 q4 = *(const ushort4*)(O1 + (size_t)node * 1024 + choff);
    float4 qv = make_float4(bf2f(q4.x), bf2f(q4.y), bf2f(q4.z), bf2f(q4.w));
    float pd = bf2f(O1[(size_t)node * 1024 + 896 + lane]);

    int j = row[node], jend = row[node + 1];
    float m = -INFINITY, l = 0.f, wacc = 0.f;
    float4 acc = make_float4(0.f, 0.f, 0.f, 0.f);

    ushort4 k4n = make_ushort4(0,0,0,0), v4n = make_ushort4(0,0,0,0);
    float ea_n = 0.f;
    if (j < jend) {
        int e = eid[j], s = src[e];
        k4n = *(const ushort4*)(O1 + (size_t)s * 1024 + 256 + choff);
        v4n = *(const ushort4*)(O1 + (size_t)s * 1024 + 512 + choff);
        ea_n = EA[(size_t)e * 32 + hl];
    }
    while (j < jend) {
        ushort4 k4 = k4n, v4 = v4n;
        float eav = ea_n;
        j++;
        if (j < jend) {
            int e = eid[j], s = src[e];
            k4n = *(const ushort4*)(O1 + (size_t)s * 1024 + 256 + choff);
            v4n = *(const ushort4*)(O1 + (size_t)s * 1024 + 512 + choff);
            ea_n = EA[(size_t)e * 32 + hl];
        }
        float part = qv.x*bf2f(k4.x) + qv.y*bf2f(k4.y) + qv.z*bf2f(k4.z) + qv.w*bf2f(k4.w)
                   + pd * eav;
        #pragma unroll
        for (int off = 16; off >= 1; off >>= 1) part += __shfl_xor(part, off);
        float a = part * inv;
        float mn = fmaxf(m, a);
        float scale = __expf(m - mn);
        float w = __expf(a - mn);
        l = l * scale + w;
        acc.x = acc.x * scale + w * bf2f(v4.x);
        acc.y = acc.y * scale + w * bf2f(v4.y);
        acc.z = acc.z * scale + w * bf2f(v4.z);
        acc.w = acc.w * scale + w * bf2f(v4.w);
        wacc = wacc * scale + w * eav;
        m = mn;
    }
    float r = 1.f / (l + 1e-16f);
    acc.x *= r; acc.y *= r; acc.z *= r; acc.w *= r;
    *(float4*)(agg + (size_t)node * 256 + choff) = acc;
    wea[(size_t)node * 64 + lane] = wacc * r;
}

// ---------------- LayerNorm passes ------------------------------------------
// h = LN1(x + 0.5*(agg_h0+agg_h1) + skip_bf16)  -> bf16
__global__ __launch_bounds__(256)
void node_ln1(const float* __restrict__ x, const float* __restrict__ agg,
              const unsigned short* __restrict__ O1, const float* __restrict__ g,
              const float* __restrict__ b, unsigned short* __restrict__ hout, int N) {
    int node = blockIdx.x * 4 + (threadIdx.x >> 6);
    if (node >= N) return;
    int lane = threadIdx.x & 63;
    float2 xv = ((const float2*)(x   + (size_t)node*128))[lane];
    float2 a0 = ((const float2*)(agg + (size_t)node*256))[lane];
    float2 a1 = ((const float2*)(agg + (size_t)node*256 + 128))[lane];
    ushort2 s2 = *(const ushort2*)(O1 + (size_t)node*1024 + 768 + lane*2);
    float t0 = xv.x + 0.5f*(a0.x + a1.x) + bf2f(s2.x);
    float t1 = xv.y + 0.5f*(a0.y + a1.y) + bf2f(s2.y);
    float s = t0 + t1;
    #pragma unroll
    for (int off = 32; off >= 1; off >>= 1) s += __shfl_xor(s, off);
    float mu = s * (1.f/128.f);
    float d0 = t0 - mu, d1 = t1 - mu;
    float q = d0*d0 + d1*d1;
    #pragma unroll
    for (int off = 32; off >= 1; off >>= 1) q += __shfl_xor(q, off);
    float rs = rsqrtf(q * (1.f/128.f) + 1e-5f);
    float2 gv = ((const float2*)g)[lane], bv = ((const float2*)b)[lane];
    ushort2 o;
    o.x = f2bf(d0*rs*gv.x + bv.x);
    o.y = f2bf(d1*rs*gv.y + bv.y);
    *(ushort2*)(hout + (size_t)node*128 + lane*2) = o;
}

// out = LN2(h_bf16 + f)
__global__ __launch_bounds__(256)
void node_ln2(const unsigned short* __restrict__ hb, const float* __restrict__ f,
              const float* __restrict__ g, const float* __restrict__ b,
              float* __restrict__ out, int N) {
    int node = blockIdx.x * 4 + (threadIdx.x >> 6);
    if (node >= N) return;
    int lane = threadIdx.x & 63;
    ushort2 h2 = *(const ushort2*)(hb + (size_t)node*128 + lane*2);
    float2 fv = ((const float2*)(f + (size_t)node*128))[lane];
    float t0 = bf2f(h2.x) + fv.x;
    float t1 = bf2f(h2.y) + fv.y;
    float s = t0 + t1;
    #pragma unroll
    for (int off = 32; off >= 1; off >>= 1) s += __shfl_xor(s, off);
    float mu = s * (1.f/128.f);
    float d0 = t0 - mu, d1 = t1 - mu;
    float q = d0*d0 + d1*d1;
    #pragma unroll
    for (int off = 32; off >= 1; off >>= 1) q += __shfl_xor(q, off);
    float rs = rsqrtf(q * (1.f/128.f) + 1e-5f);
    float2 gv = ((const float2*)g)[lane], bv = ((const float2*)b)[lane];
    float2 o;
    o.x = d0*rs*gv.x + bv.x;
    o.y = d1*rs*gv.y + bv.y;
    ((float2*)(out + (size_t)node*128))[lane] = o;
}

// ---------------------------------------------------------------------------
extern "C" void kernel_launch(void* const* d_in, const int* in_sizes, int n_in,
                              void* d_out, int out_size, void* d_ws, size_t ws_size,
                              hipStream_t stream) {
    const float* x    = (const float*)d_in[0];
    const int*   ei   = (const int*)d_in[1];
    const float* ea   = (const float*)d_in[2];
    const float* Wq   = (const float*)d_in[3];
    const float* bq   = (const float*)d_in[4];
    const float* Wk   = (const float*)d_in[5];
    const float* bk   = (const float*)d_in[6];
    const float* Wv   = (const float*)d_in[7];
    const float* bv   = (const float*)d_in[8];
    const float* We   = (const float*)d_in[9];
    const float* Wsk  = (const float*)d_in[10];
    const float* bsk  = (const float*)d_in[11];
    const float* g1   = (const float*)d_in[12];
    const float* b1l  = (const float*)d_in[13];
    const float* W1   = (const float*)d_in[14];
    const float* b1f  = (const float*)d_in[15];
    const float* W2   = (const float*)d_in[16];
    const float* b2f  = (const float*)d_in[17];
    const float* g2   = (const float*)d_in[18];
    const float* b2l  = (const float*)d_in[19];
    float* out = (float*)d_out;

    const int N = in_sizes[0] / 128;
    const int E = in_sizes[2] / 32;
    const int* src = ei;
    const int* dst = ei + E;

    char* w = (char*)d_ws;
    unsigned short* O1   = (unsigned short*)w;  w += (size_t)N * 2048;  // [N,1024] bf16
    float* agg           = (float*)w;           w += (size_t)N * 1024;  // [N,256] f32
    float* wea           = (float*)w;           w += (size_t)N * 256;   // [N,64] f32
    unsigned short* xh   = (unsigned short*)w;  w += (size_t)N * 256;   // [N,128] bf16
    unsigned short* hb   = (unsigned short*)w;  w += (size_t)N * 256;   // [N,128] bf16
    unsigned short* Wcat = (unsigned short*)w;  w += 1024 * 128 * 2;
    float* bcat          = (float*)w;           w += 1024 * 4;
    unsigned short* W1h  = (unsigned short*)w;  w += 256 * 128 * 2;
    unsigned short* W2h  = (unsigned short*)w;  w += 128 * 256 * 2;
    float* wcb           = (float*)w;           w += 8256 * 4;
    int* deg  = (int*)w;
    int* cnt  = deg + N;
    int* tmp  = cnt + N;
    int* rowp = tmp + N;            // N+1
    int* bsum = rowp + N + 1;       // <=1024
    int* eid  = bsum + 1024;        // E

    // mid (bf16 [N,256]) and f (f32 [N,128]) alias agg (free after LN1)
    unsigned short* mid = (unsigned short*)agg;
    float* fbuf = (float*)((char*)agg + (size_t)N * 512);

    const int gy  = (N + 63) / 64;
    const int gy128 = (N + 127) / 128;
    const int nb  = (N + 255) / 256;

    // ---- weight/input prep (bf16) ----
    f32_to_bf16<<<(N*128 + 255)/256, 256, 0, stream>>>(x, xh, N*128);
    wcomb_k<<<33, 256, 0, stream>>>(Wq, bq, We, wcb);
    pack_wcat<<<(1024*128 + 255)/256, 256, 0, stream>>>(Wq, Wk, Wv, Wsk, wcb, Wcat);
    pack_bcat<<<4, 256, 0, stream>>>(bq, bk, bv, bsk, wcb, bcat);
    f32_to_bf16<<<128, 256, 0, stream>>>(W1, W1h, 256*128);
    f32_to_bf16<<<128, 256, 0, stream>>>(W2, W2h, 128*256);

    // ---- fused projection GEMM: OUT1 = xh @ Wcat^T + bcat ----
    gemm_mfma<0,1><<<dim3(8, gy128), 256, 0, stream>>>(xh, 128, Wcat, 128, bcat,
                                                       O1, 1024, N, 128);

    // ---- CSR build ----
    zero_int<<<(2*N + 255)/256, 256, 0, stream>>>(deg, 2*N);   // deg + cnt
    deg_count<<<(E + 255)/256, 256, 0, stream>>>(dst, deg, E);
    scan_block<<<nb, 256, 0, stream>>>(deg, tmp, bsum, N);
    scan_bsum<<<1, 1024, 0, stream>>>(bsum, nb);
    scan_finalize<<<nb, 256, 0, stream>>>(tmp, bsum, rowp, N);
    csr_fill<<<(E + 255)/256, 256, 0, stream>>>(dst, rowp, cnt, eid, E);

    // ---- attention ----
    fused_attn<<<(N + 3)/4, 256, 0, stream>>>(O1, ea, src, rowp, eid, agg, wea, N);

    // e-contribution: agg[:,h,:] += wea[:,h,:] @ We_h^T  (fp32, tiny)
    gemm_tn<0,1><<<dim3(2, gy), 256, 0, stream>>>(wea,      64, We,          32, nullptr, agg,       256, N, 32, 128);
    gemm_tn<0,1><<<dim3(2, gy), 256, 0, stream>>>(wea + 32, 64, We + 128*32, 32, nullptr, agg + 128, 256, N, 32, 128);

    // h = LN1(x + mean_heads(agg) + skip) -> bf16
    node_ln1<<<(N + 3)/4, 256, 0, stream>>>(x, agg, O1, g1, b1l, hb, N);

    // FFN (bf16 MFMA)
    gemm_mfma<1,1><<<dim3(2, gy128), 256, 0, stream>>>(hb, 128, W1h, 128, b1f,
                                                       mid, 256, N, 128);
    gemm_mfma<0,0><<<dim3(1, gy128), 256, 0, stream>>>(mid, 256, W2h, 256, b2f,
                                                       fbuf, 128, N, 256);

    // out = LN2(h + f)
    node_ln2<<<(N + 3)/4, 256, 0, stream>>>(hb, fbuf, g2, b2l, out, N);
}